// Round 21
// baseline (13.395 us; speedup 1.0000x reference)
//
#include <hip/hip_runtime.h>
#include <hip/hip_bf16.h>

#define NE    16
#define INF   512
#define OUTF  512
#define NT    2048
#define OTILE 32          // out-cols per block (2 o-subtiles of 16)
#define TCH   32          // tokens per chunk (2 t-subtiles of 16)
#define NZ    2           // token-chunk split across blocks
#define LSTRIDE 520       // LDS row stride in bf16 elems (512 + 8 pad)

#define SZ_W   (OTILE * LSTRIDE * 2)            // 33280 B
#define SZ_X   (TCH * LSTRIDE * 2)              // 33280 B
#define SZ_LST ((NT + TCH) * 4)                 // 8320 B
#define SMEM_BYTES (SZ_W + SZ_X + SZ_LST + 64)  // ~75 KB -> 2 blocks/CU

typedef __attribute__((ext_vector_type(4))) float f32x4;
typedef __attribute__((ext_vector_type(8))) short bf16x8;
typedef __attribute__((ext_vector_type(4))) short bf16x4;

__device__ inline unsigned short f2bf(float f) {
    union { __hip_bfloat16 h; unsigned short s; } u;
    u.h = __float2bfloat16(f);
    return u.s;
}

__device__ inline bf16x4 cvt4(f32x4 v) {
    bf16x4 r;
    r[0] = (short)f2bf(v[0]); r[1] = (short)f2bf(v[1]);
    r[2] = (short)f2bf(v[2]); r[3] = (short)f2bf(v[3]);
    return r;
}

__global__ __launch_bounds__(256, 2)
void switch_linear_kernel(const float* __restrict__ x,
                          const int* __restrict__ idx,
                          const float* __restrict__ W,
                          const float* __restrict__ bias,
                          float* __restrict__ out)
{
    extern __shared__ char smem[];
    short* s_W    = (short*)smem;                      // [OTILE][LSTRIDE]
    short* s_X    = (short*)(smem + SZ_W);             // [TCH][LSTRIDE]
    int*   s_list = (int*)(smem + SZ_W + SZ_X);
    int*   s_wcnt = (int*)(smem + SZ_W + SZ_X + SZ_LST);

    const int b   = blockIdx.x;
    const int e   = b & 15;               // expert; all blocks of e on XCD e%8
    const int oj  = (b >> 4) & 15;        // o-tile index (stagger phase)
    const int o0  = oj * OTILE;
    const int z   = b >> 8;               // token-chunk phase 0..1
    const int tid = threadIdx.x;
    const int lane = tid & 63;
    const int wv   = tid >> 6;            // 0..3

    // ---- Phase A: idx loads (8 iters/thread at 256 threads) ----
    int iv[8];
#pragma unroll
    for (int it = 0; it < 8; ++it)
        iv[it] = idx[wv * 512 + it * 64 + lane];

    // ---- Phase B: stage W tile (32 rows x 512 f32) -> LDS bf16.
    // z-pair blocks share this tile; stage halves in OPPOSITE order so each
    // half is HBM-fetched once and L2-hit by the partner. ----
    const float* wbase = W + ((size_t)e * OUTF + o0) * INF;
#pragma unroll
    for (int i = 0; i < 16; ++i) {
        const int ii = z ? ((i + 8) & 15) : i;
        const int li = tid + ii * 256;           // f32x4 index, 0..4095
        f32x4 v = ((const f32x4*)wbase)[li];
        const int row = li >> 7;
        const int col = (li * 4) & 511;
        *(bf16x4*)(&s_W[row * LSTRIDE + col]) = cvt4(v);
    }

    // ---- Blanket x prefetch: stream slice b/512 of x (8 KB) to warm L2/L3.
    // Bytes are needed later anyway; latency overlaps the ballot phase. ----
    {
        const f32x4* xpf = (const f32x4*)x + (size_t)b * 512 + tid;
        f32x4 p0 = xpf[0];
        f32x4 p1 = xpf[256];
        float s = p0[0] + p1[3];
        asm volatile("" :: "v"(s));       // keep loads alive
    }

    // ---- Phase C: ballot-compaction token list ----
    unsigned long long masks[8];
    int wtot = 0;
#pragma unroll
    for (int it = 0; it < 8; ++it) {
        const unsigned long long mk = __ballot(iv[it] == e);
        masks[it] = mk;
        wtot += __popcll(mk);
    }
    if (lane == 0) s_wcnt[wv] = wtot;
    __syncthreads();
    int base = 0;
#pragma unroll
    for (int w = 0; w < 4; ++w) { int c = s_wcnt[w]; if (w < wv) base += c; }
    const int cnt = s_wcnt[0] + s_wcnt[1] + s_wcnt[2] + s_wcnt[3];
    const unsigned long long below = (1ull << lane) - 1ull;
    int run = base;
#pragma unroll
    for (int it = 0; it < 8; ++it) {
        const unsigned long long mk = masks[it];
        if (mk & (1ull << lane))
            s_list[run + __popcll(mk & below)] = wv * 512 + it * 64 + lane;
        run += __popcll(mk);
    }
    const int cnt_pad = (cnt + TCH - 1) & ~(TCH - 1);
    for (int i = cnt + tid; i < cnt_pad; i += 256) s_list[i] = -1;
    __syncthreads();                      // s_list + s_W ready
    if (cnt == 0) return;

    // ---- Wave layout: 4 waves = 2 (token) x 2 (out) sub-tiles of 16 ----
    const int wt = wv >> 1;    // token sub-tile 0..1
    const int wo = wv & 1;     // out   sub-tile 0..1
    const int lr = lane & 15;
    const int q  = lane >> 4;
    const int orow = o0 + wo * 16 + lr;

    // ---- W fragments into REGISTERS (once) ----
    bf16x8 bfr[16];
#pragma unroll
    for (int kk = 0; kk < 16; ++kk)
        bfr[kk] = *(const bf16x8*)(&s_W[(wo * 16 + lr) * LSTRIDE + kk * 32 + q * 8]);
    const float bv = bias[e * OUTF + orow];

    // x-staging mapping: 8 threads per token row (32 rows), 16 f32x4/thread
    const int slot = tid >> 3;            // 0..31
    const int sub  = tid & 7;

    const int nch = cnt_pad / TCH;
    const int M = (nch - z + NZ - 1) / NZ;
    if (M <= 0) return;
    const int m0 = oj % M;

    // ---- initial stage: chunk m0 -> s_X ----
    f32x4 xreg[16];
    {
        const int cb = (z + m0 * NZ) * TCH;
        int tok_s = s_list[cb + slot];
        if (tok_s < 0) tok_s = 0;
        const f32x4* xr = (const f32x4*)(x + (size_t)tok_s * INF);
#pragma unroll
        for (int i = 0; i < 16; ++i) xreg[i] = xr[sub + i * 8];
#pragma unroll
        for (int i = 0; i < 16; ++i)
            *(bf16x4*)(&s_X[slot * LSTRIDE + (sub + i * 8) * 4]) = cvt4(xreg[i]);
    }
    __syncthreads();                      // s_X published

    for (int k = 0; k < M; ++k) {
        int m = m0 + k; if (m >= M) m -= M;
        const int cb = (z + m * NZ) * TCH;
        const bool more = (k + 1) < M;

        // ---- T14: issue next chunk's loads BEFORE compute (latency hides) ----
        if (more) {
            int mn = m0 + k + 1; if (mn >= M) mn -= M;
            const int cbn = (z + mn * NZ) * TCH;
            int tok_s = s_list[cbn + slot];
            if (tok_s < 0) tok_s = 0;
            const f32x4* xr = (const f32x4*)(x + (size_t)tok_s * INF);
#pragma unroll
            for (int i = 0; i < 16; ++i) xreg[i] = xr[sub + i * 8];
        }

        // ---- compute: 16 MFMAs/wave, A from LDS, B from registers ----
        f32x4 acc = {0.f, 0.f, 0.f, 0.f};
#pragma unroll
        for (int kk = 0; kk < 16; ++kk) {
            bf16x8 afr = *(const bf16x8*)(&s_X[(wt * 16 + lr) * LSTRIDE + kk * 32 + q * 8]);
            acc = __builtin_amdgcn_mfma_f32_16x16x32_bf16(afr, bfr[kk], acc, 0, 0, 0);
        }
        // ---- epilogue: D row = q*4+j (token), col = lr ----
#pragma unroll
        for (int j = 0; j < 4; ++j) {
            const int tok = s_list[cb + wt * 16 + q * 4 + j];
            if (tok >= 0) out[(size_t)tok * OUTF + orow] = acc[j] + bv;
        }

        if (more) {
            __syncthreads();              // drain all reads of s_X
#pragma unroll
            for (int i = 0; i < 16; ++i)
                *(bf16x4*)(&s_X[slot * LSTRIDE + (sub + i * 8) * 4]) = cvt4(xreg[i]);
            __syncthreads();              // publish next chunk
        }
    }
}

extern "C" void kernel_launch(void* const* d_in, const int* in_sizes, int n_in,
                              void* d_out, int out_size, void* d_ws, size_t ws_size,
                              hipStream_t stream) {
    const float* x    = (const float*)d_in[0];
    const int*   idx  = (const int*)d_in[1];
    const float* W    = (const float*)d_in[2];
    const float* bias = (const float*)d_in[3];
    float* out = (float*)d_out;

    dim3 grid(NE * 16 * NZ);   // 16 e x 16 o-tiles x 2 z = 512 blocks, 2/CU
    dim3 block(256);           // 4 waves
    switch_linear_kernel<<<grid, block, SMEM_BYTES, stream>>>(x, idx, W, bias, out);
}

// Round 22
// 12.939 us; speedup vs baseline: 1.0352x; 1.0352x over previous
//
#include <hip/hip_runtime.h>
#include <hip/hip_bf16.h>

#define NE    16
#define INF   512
#define OUTF  512
#define NT    2048
#define OTILE 32          // out-cols per block (2 o-subtiles of 16)
#define TCH   32          // tokens per chunk (2 t-subtiles of 16)
#define NZ    2           // token-chunk split across blocks
#define LSTRIDE 520       // LDS row stride in bf16 elems (512 + 8 pad)

#define SZ_W   (OTILE * LSTRIDE * 2)            // 33280 B
#define SZ_X   (TCH * LSTRIDE * 2)              // 33280 B
#define SZ_LST ((NT + TCH) * 4)                 // 8320 B
#define SMEM_BYTES (SZ_W + SZ_X + SZ_LST + 64)  // ~75 KB -> 2 blocks/CU

typedef __attribute__((ext_vector_type(4))) float f32x4;
typedef __attribute__((ext_vector_type(8))) short bf16x8;
typedef __attribute__((ext_vector_type(4))) short bf16x4;

__device__ inline unsigned short f2bf(float f) {
    union { __hip_bfloat16 h; unsigned short s; } u;
    u.h = __float2bfloat16(f);
    return u.s;
}

__device__ inline bf16x4 cvt4(f32x4 v) {
    bf16x4 r;
    r[0] = (short)f2bf(v[0]); r[1] = (short)f2bf(v[1]);
    r[2] = (short)f2bf(v[2]); r[3] = (short)f2bf(v[3]);
    return r;
}

__global__ __launch_bounds__(256, 2)
void switch_linear_kernel(const float* __restrict__ x,
                          const int* __restrict__ idx,
                          const float* __restrict__ W,
                          const float* __restrict__ bias,
                          float* __restrict__ out)
{
    extern __shared__ char smem[];
    short* s_W    = (short*)smem;                      // [OTILE][LSTRIDE]
    short* s_X    = (short*)(smem + SZ_W);             // [TCH][LSTRIDE]
    int*   s_list = (int*)(smem + SZ_W + SZ_X);
    int*   s_wcnt = (int*)(smem + SZ_W + SZ_X + SZ_LST);

    const int b   = blockIdx.x;
    const int e   = b & 15;               // expert; all blocks of e on XCD e%8
    const int oj  = (b >> 4) & 15;        // o-tile index (stagger phase)
    const int o0  = oj * OTILE;
    const int z   = b >> 8;               // token-chunk phase 0..1
    const int tid = threadIdx.x;
    const int lane = tid & 63;
    const int wv   = tid >> 6;            // 0..3

    // ---- Phase A: idx loads (8 iters/thread at 256 threads) ----
    int iv[8];
#pragma unroll
    for (int it = 0; it < 8; ++it)
        iv[it] = idx[wv * 512 + it * 64 + lane];

    // ---- Phase B: stage W tile (32 rows x 512 f32, contiguous) -> LDS bf16 ----
    const float* wbase = W + ((size_t)e * OUTF + o0) * INF;
#pragma unroll
    for (int i = 0; i < 16; ++i) {
        const int li = tid + i * 256;            // f32x4 index, 0..4095
        f32x4 v = ((const f32x4*)wbase)[li];
        const int row = li >> 7;
        const int col = (li * 4) & 511;
        *(bf16x4*)(&s_W[row * LSTRIDE + col]) = cvt4(v);
    }

    // ---- Phase C: ballot-compaction token list ----
    unsigned long long masks[8];
    int wtot = 0;
#pragma unroll
    for (int it = 0; it < 8; ++it) {
        const unsigned long long mk = __ballot(iv[it] == e);
        masks[it] = mk;
        wtot += __popcll(mk);
    }
    if (lane == 0) s_wcnt[wv] = wtot;
    __syncthreads();
    int base = 0;
#pragma unroll
    for (int w = 0; w < 4; ++w) { int c = s_wcnt[w]; if (w < wv) base += c; }
    const int cnt = s_wcnt[0] + s_wcnt[1] + s_wcnt[2] + s_wcnt[3];
    const unsigned long long below = (1ull << lane) - 1ull;
    int run = base;
#pragma unroll
    for (int it = 0; it < 8; ++it) {
        const unsigned long long mk = masks[it];
        if (mk & (1ull << lane))
            s_list[run + __popcll(mk & below)] = wv * 512 + it * 64 + lane;
        run += __popcll(mk);
    }
    const int cnt_pad = (cnt + TCH - 1) & ~(TCH - 1);
    for (int i = cnt + tid; i < cnt_pad; i += 256) s_list[i] = -1;
    __syncthreads();                      // s_list + s_W ready
    if (cnt == 0) return;

    // ---- Wave layout: 4 waves = 2 (token) x 2 (out) sub-tiles of 16 ----
    const int wt = wv >> 1;    // token sub-tile 0..1
    const int wo = wv & 1;     // out   sub-tile 0..1
    const int lr = lane & 15;
    const int q  = lane >> 4;
    const int orow = o0 + wo * 16 + lr;

    // ---- W fragments into REGISTERS (once) ----
    bf16x8 bfr[16];
#pragma unroll
    for (int kk = 0; kk < 16; ++kk)
        bfr[kk] = *(const bf16x8*)(&s_W[(wo * 16 + lr) * LSTRIDE + kk * 32 + q * 8]);
    const float bv = bias[e * OUTF + orow];

    // x-staging mapping: 8 threads per token row (32 rows), 16 f32x4/thread
    const int slot = tid >> 3;            // 0..31
    const int sub  = tid & 7;

    const int nch = cnt_pad / TCH;
    const int M = (nch - z + NZ - 1) / NZ;
    if (M <= 0) return;
    const int m0 = oj % M;

    for (int k = 0; k < M; ++k) {
        int m = m0 + k; if (m >= M) m -= M;
        const int cb = (z + m * NZ) * TCH;

        int tok_s = s_list[cb + slot];
        if (tok_s < 0) tok_s = 0;
        const f32x4* xr = (const f32x4*)(x + (size_t)tok_s * INF);
        f32x4 xreg[16];
#pragma unroll
        for (int i = 0; i < 16; ++i) xreg[i] = xr[sub + i * 8];
#pragma unroll
        for (int i = 0; i < 16; ++i)
            *(bf16x4*)(&s_X[slot * LSTRIDE + (sub + i * 8) * 4]) = cvt4(xreg[i]);
        __syncthreads();                  // s_X ready

        f32x4 acc = {0.f, 0.f, 0.f, 0.f};
#pragma unroll
        for (int kk = 0; kk < 16; ++kk) {
            bf16x8 afr = *(const bf16x8*)(&s_X[(wt * 16 + lr) * LSTRIDE + kk * 32 + q * 8]);
            acc = __builtin_amdgcn_mfma_f32_16x16x32_bf16(afr, bfr[kk], acc, 0, 0, 0);
        }
#pragma unroll
        for (int j = 0; j < 4; ++j) {
            const int tok = s_list[cb + wt * 16 + q * 4 + j];
            if (tok >= 0) out[(size_t)tok * OUTF + orow] = acc[j] + bv;
        }
        if (k != M - 1) __syncthreads();  // reads done before next restage
    }
}

extern "C" void kernel_launch(void* const* d_in, const int* in_sizes, int n_in,
                              void* d_out, int out_size, void* d_ws, size_t ws_size,
                              hipStream_t stream) {
    const float* x    = (const float*)d_in[0];
    const int*   idx  = (const int*)d_in[1];
    const float* W    = (const float*)d_in[2];
    const float* bias = (const float*)d_in[3];
    float* out = (float*)d_out;

    dim3 grid(NE * 16 * NZ);   // 16 e x 16 o-tiles x 2 z = 512 blocks, 2/CU
    dim3 block(256);           // 4 waves
    switch_linear_kernel<<<grid, block, SMEM_BYTES, stream>>>(x, idx, W, bias, out);
}